// Round 4
// baseline (366.836 us; speedup 1.0000x reference)
//
#include <hip/hip_runtime.h>
#include <hip/hip_bf16.h>

// SelfAttention non-local block: B=8, C=512, N=4096, CQK=32.  All-MFMA bf16 path.
// v7:
//  - k_pass2 chunk reorder: all 4 produce tiles (register-only inputs) moved to
//    directly after the barrier + P-read issues. v6 buried them behind the P-read
//    lgkm waits, so the post-barrier LDS burst (8 waves x 8 b128 = ~570 cyc) ran
//    with an idle MFMA pipe and no cross-wave fill (2 waves/SIMD, barrier-locked).
//  - consume re-split by m-half (half1: 8 nt x va0/m0..31, half2: 8 nt x va1):
//    va0 dies after half1 -> loadV0(chunk+1) issues mid-chunk and its L2 latency
//    hides under half2, instead of all V loads draining at the barrier vmcnt(0).
//    r-reads issued per-nt inside half1 (register-neutral: pg[nt] dies, rr[nt] born).
//  - k_proj: B-frags software-pipelined one k-step ahead (wrap-indexed).
// ws: vb 33.5MB | xT 33.5MB | qb 2MB | kb 2MB | Wvb 512KB | Wqb 32KB | Wkb 32KB | Lneg 128KB

typedef __attribute__((ext_vector_type(8))) short s16x8;
typedef __attribute__((ext_vector_type(4))) float f32x4;

#define MFMA16(a, b, c) __builtin_amdgcn_mfma_f32_16x16x32_bf16((a), (b), (c), 0, 0, 0)

__device__ __forceinline__ ushort f2bf(float f) {
  union { float f; unsigned u; } v; v.f = f;
  return (ushort)((v.u + 0x8000u) >> 16);
}
__device__ __forceinline__ unsigned pack_bf16(float lo, float hi) {  // (hi<<16)|lo
  union { float f; unsigned u; } a, b; a.f = lo; b.f = hi;
  return __builtin_amdgcn_perm(b.u + 0x8000u, a.u + 0x8000u, 0x07060302u);
}
__device__ __forceinline__ float fexp2(float x) { return __builtin_amdgcn_exp2f(x); }

// ---------------- kernel 1: weights -> bf16 (Wq pre-scaled by log2e) ----------------
__global__ void k_cvt_w(const float* __restrict__ Wq, const float* __restrict__ Wk,
                        const float* __restrict__ Wv, ushort* __restrict__ Wqb,
                        ushort* __restrict__ Wkb, ushort* __restrict__ Wvb) {
  int i = blockIdx.x * 256 + threadIdx.x;
  if (i < 262144) Wvb[i] = f2bf(Wv[i]);
  else if (i < 278528) Wqb[i - 262144] = f2bf(Wq[i - 262144] * 1.4426950408889634f);
  else if (i < 294912) Wkb[i - 278528] = f2bf(Wk[i - 278528]);
}

// ---------------- kernel 2: transpose x -> xT bf16 ----------------
// Tile 64c x 256n. Phase1: float4 row loads (1KB contiguous per row), pack n-pairs,
// SoA LDS U[2][64][65] (even/odd pair split => <=2-way banks). Phase2: 8-lane groups
// build 128B-contiguous xT rows via v_perm extraction.
__global__ __launch_bounds__(256) void k_xpose(const float* __restrict__ x,
                                               ushort* __restrict__ xT) {
  const int b = blockIdx.z, c0 = blockIdx.y * 64, n0 = blockIdx.x * 256;
  __shared__ uint U[2][64][65];
  const int t = threadIdx.x;
  const int wv = t >> 6, ln = t & 63;
  const float* xp = x + ((size_t)b * 512 + c0 + wv * 16) * 4096 + n0 + ln * 4;
#pragma unroll
  for (int i = 0; i < 16; ++i) {
    float4 f = *(const float4*)(xp + (size_t)i * 4096);
    U[0][wv * 16 + i][ln] = pack_bf16(f.x, f.y);   // pairs (4ln,4ln+1)   -> pair idx 2ln
    U[1][wv * 16 + i][ln] = pack_bf16(f.z, f.w);   // pairs (4ln+2,4ln+3) -> pair idx 2ln+1
  }
  __syncthreads();
  const int c_seg = (t & 7) * 8;
#pragma unroll
  for (int pass = 0; pass < 8; ++pass) {
    const int nl = pass * 32 + (t >> 3);
    const int p = nl >> 1;              // pair index
    const int h = p & 1, idx = p >> 1;  // SoA half, slot
    const uint sel = (nl & 1) ? 0x07060302u : 0x05040100u;
    uint o[4];
#pragma unroll
    for (int j = 0; j < 4; ++j) {
      uint ua = U[h][c_seg + 2 * j][idx];
      uint ub = U[h][c_seg + 2 * j + 1][idx];
      o[j] = __builtin_amdgcn_perm(ub, ua, sel);   // (bf(c_odd)<<16)|bf(c_even)
    }
    *(uint4*)(xT + ((size_t)b * 4096 + n0 + nl) * 512 + c0 + c_seg) = *(uint4*)o;
  }
}

// ---------------- kernel 3: fused q/k/v projection from xT ----------------
__global__ __launch_bounds__(256, 2) void k_proj(const ushort* __restrict__ xT,
                                                 const ushort* __restrict__ Wqb,
                                                 const ushort* __restrict__ Wkb,
                                                 const ushort* __restrict__ Wvb,
                                                 ushort* __restrict__ qb,
                                                 ushort* __restrict__ kb,
                                                 ushort* __restrict__ vb) {
  const int b = blockIdx.y, n0 = blockIdx.x * 64;
  const int lane = threadIdx.x & 63, w = threadIdx.x >> 6;
  const int quad = lane >> 4, l15 = lane & 15;
  const ushort* xT_b = xT + (size_t)b * 4096 * 512;

  const ushort* Wqk = (w < 2) ? (Wqb + (size_t)(w * 16 + l15) * 512)
                              : (Wkb + (size_t)((w - 2) * 16 + l15) * 512);

  f32x4 accv[8][4], accqk[4];
#pragma unroll
  for (int i = 0; i < 8; ++i)
#pragma unroll
    for (int nt = 0; nt < 4; ++nt) accv[i][nt] = {0.f, 0.f, 0.f, 0.f};
#pragma unroll
  for (int nt = 0; nt < 4; ++nt) accqk[nt] = {0.f, 0.f, 0.f, 0.f};

  s16x8 bx[4], bxn[4];
#pragma unroll
  for (int nt = 0; nt < 4; ++nt)
    bx[nt] = *(const s16x8*)(xT_b + (size_t)(n0 + nt * 16 + l15) * 512 + quad * 8);

  for (int k0 = 0; k0 < 512; k0 += 32) {
    const int kn = (k0 + 32) & 511;   // wrap: always in-bounds, dead on last iter
#pragma unroll
    for (int nt = 0; nt < 4; ++nt)
      bxn[nt] = *(const s16x8*)(xT_b + (size_t)(n0 + nt * 16 + l15) * 512 + kn + quad * 8);
#pragma unroll
    for (int i = 0; i < 8; ++i) {
      s16x8 av = *(const s16x8*)(Wvb + (size_t)((8 * w + i) * 16 + l15) * 512 + k0 + quad * 8);
#pragma unroll
      for (int nt = 0; nt < 4; ++nt) accv[i][nt] = MFMA16(av, bx[nt], accv[i][nt]);
    }
    s16x8 aqk = *(const s16x8*)(Wqk + k0 + quad * 8);
#pragma unroll
    for (int nt = 0; nt < 4; ++nt) accqk[nt] = MFMA16(aqk, bx[nt], accqk[nt]);
#pragma unroll
    for (int nt = 0; nt < 4; ++nt) bx[nt] = bxn[nt];
  }

  ushort* vb_b = vb + (size_t)b * 512 * 4096;
#pragma unroll
  for (int i = 0; i < 8; ++i)
#pragma unroll
    for (int nt = 0; nt < 4; ++nt)
#pragma unroll
      for (int r = 0; r < 4; ++r)
        vb_b[(size_t)((8 * w + i) * 16 + quad * 4 + r) * 4096 + n0 + nt * 16 + l15] =
            f2bf(accv[i][nt][r]);

  ushort* qk_out = (w < 2) ? (qb + (size_t)b * 4096 * 32) : (kb + (size_t)b * 4096 * 32);
#pragma unroll
  for (int nt = 0; nt < 4; ++nt) {
    ushort4 u;
    u.x = f2bf(accqk[nt][0]); u.y = f2bf(accqk[nt][1]);
    u.z = f2bf(accqk[nt][2]); u.w = f2bf(accqk[nt][3]);
    *(ushort4*)(qk_out + (size_t)(n0 + nt * 16 + l15) * 32 + (w & 1) * 16 + quad * 4) = u;
  }
}

// ---------------- kernel 4: pass1 — Lneg[b][m] = -log2(sum_n 2^(S'[m,n])) ----------------
__global__ __launch_bounds__(256) void k_pass1(const ushort* __restrict__ qb,
                                               const ushort* __restrict__ kb,
                                               float* __restrict__ Lneg) {
  const int b = blockIdx.y, mt = blockIdx.x;
  const int lane = threadIdx.x & 63, w = threadIdx.x >> 6;
  const int quad = lane >> 4, l15 = lane & 15;
  const int m = mt * 64 + w * 16;
  const ushort* qb_b = qb + (size_t)b * 4096 * 32;
  const ushort* kb_b = kb + (size_t)b * 4096 * 32;
  const s16x8 aqf = *(const s16x8*)(qb_b + (size_t)(m + l15) * 32 + quad * 8);
  float ps[4] = {0.f, 0.f, 0.f, 0.f};
  const f32x4 zf = {0.f, 0.f, 0.f, 0.f};
  for (int n0 = 0; n0 < 4096; n0 += 64) {
#pragma unroll
    for (int nt = 0; nt < 4; ++nt) {
      s16x8 bk = *(const s16x8*)(kb_b + (size_t)(n0 + nt * 16 + l15) * 32 + quad * 8);
      f32x4 s = MFMA16(aqf, bk, zf);
#pragma unroll
      for (int r = 0; r < 4; ++r) ps[r] += fexp2(s[r]);
    }
  }
  for (int off = 1; off < 16; off <<= 1)
#pragma unroll
    for (int r = 0; r < 4; ++r) ps[r] += __shfl_xor(ps[r], off, 64);
  if (l15 == 0)
#pragma unroll
    for (int r = 0; r < 4; ++r)
      Lneg[(size_t)b * 4096 + m + quad * 4 + r] = -log2f(ps[r]);
}

// ---------------- kernel 5: pass2 — out = V @ 2^(S' + Lneg) ----------------
// Grid 256 = 8 b (XCD-aligned: blk&7) x 32 ntb. Block 8 waves (512 thr): tile
// 512c x 128n, chunk 64 m. Per chunk: barrier -> issue 8 P-reads (m0..31) ->
// produce x4 (register-only inputs; hides the LDS burst) -> loadQ -> consume
// half1 (va0, r-reads interleaved per-nt) -> loadV0 -> consume half2 (va1) ->
// loadV1.
__global__ __launch_bounds__(512, 2) void k_pass2(const ushort* __restrict__ qb,
                                                  const ushort* __restrict__ kb,
                                                  const ushort* __restrict__ vb,
                                                  const float* __restrict__ Lneg,
                                                  float* __restrict__ out) {
  const int blk = blockIdx.x;
  const int b = blk & 7, ntb = blk >> 3;
  const int nbase = ntb * 128;
  const int lane = threadIdx.x & 63, w = threadIdx.x >> 6;   // 8 waves
  const int quad = lane >> 4, l15 = lane & 15;
  const int cbase = w * 64;
  const int swz = l15 & 7;
  const int Mw = w >> 1;               // produce m-tile (0..3)
  const int Tb = (w & 1) * 4;          // produce n-tile base (0 or 4)

  __shared__ __align__(16) ushort PT[2][128 * 64];  // 32 KB; 16B-granule XOR swizzle

  const ushort* qb_b = qb + (size_t)b * 4096 * 32;
  const ushort* kb_b = kb + (size_t)b * 4096 * 32;
  const ushort* vb_b = vb + (size_t)b * 512 * 4096;
  const float* L_b = Lneg + (size_t)b * 4096;

  s16x8 kf[4];  // K rows for this wave's 4 produce n-tiles
#pragma unroll
  for (int i = 0; i < 4; ++i)
    kf[i] = *(const s16x8*)(kb_b + (size_t)(nbase + (Tb + i) * 16 + l15) * 32 + quad * 8);

  f32x4 acc[4][8];
#pragma unroll
  for (int ci = 0; ci < 4; ++ci)
#pragma unroll
    for (int nt = 0; nt < 8; ++nt) acc[ci][nt] = {0.f, 0.f, 0.f, 0.f};

  s16x8 aqp;        // prefetched q A-frag for next produce (single m-tile)
  float4 l4p;       // prefetched Lneg
  s16x8 va0[4], va1[4];  // v A-frags: m0..31 / m32..63 of current chunk

  auto loadQ = [&](int chunk) {
    const int m0 = chunk * 64;
    aqp = *(const s16x8*)(qb_b + (size_t)(m0 + Mw * 16 + l15) * 32 + quad * 8);
    l4p = *(const float4*)(L_b + m0 + Mw * 16 + quad * 4);
  };
  auto loadV0 = [&](int chunk) {
    const int m0 = chunk * 64;
#pragma unroll
    for (int ci = 0; ci < 4; ++ci)
      va0[ci] = *(const s16x8*)(vb_b + (size_t)(cbase + ci * 16 + l15) * 4096 + m0 + quad * 8);
  };
  auto loadV1 = [&](int chunk) {
    const int m0 = chunk * 64;
#pragma unroll
    for (int ci = 0; ci < 4; ++ci)
      va1[ci] = *(const s16x8*)(vb_b + (size_t)(cbase + ci * 16 + l15) * 4096 + m0 + 32 + quad * 8);
  };
  // one produce tile: QK MFMA (Lneg as C-in) -> exp2 -> pack -> ds_write.
  auto produce_tile = [&](int buf, int i) {
    char* Pw = (char*)&PT[buf][0];
    const int T = Tb + i;
    f32x4 cin; cin.x = l4p.x; cin.y = l4p.y; cin.z = l4p.z; cin.w = l4p.w;
    f32x4 s = MFMA16(aqp, kf[i], cin);               // S' + Lneg  (<= ~0)
    uint2 u;
    u.x = pack_bf16(fexp2(s.x), fexp2(s.y));
    u.y = pack_bf16(fexp2(s.z), fexp2(s.w));
    const int row = T * 16 + l15;
    const int gran = (2 * Mw + (quad >> 1)) ^ swz;
    *(uint2*)(Pw + row * 128 + gran * 16 + (quad & 1) * 8) = u;
  };

  loadQ(0);
#pragma unroll
  for (int i = 0; i < 4; ++i) produce_tile(0, i);    // prologue: produce chunk 0
  loadQ(1);
  loadV0(0);
  loadV1(0);

  for (int chunk = 0; chunk < 64; ++chunk) {
    const int buf = chunk & 1;
    __syncthreads();
    const char* P = (const char*)&PT[buf][0];
    // --- issue all half1 P reads (m0..31, nt 0..7) ---
    s16x8 pg[8];
#pragma unroll
    for (int nt = 0; nt < 8; ++nt)
      pg[nt] = *(const s16x8*)(P + (nt * 16 + l15) * 128 + (quad ^ swz) * 16);
    // --- produce chunk+1 into buf^1: register-only inputs, no dep on pg ---
    // (chunk 63's produce reuses aqp(63) and writes a never-read buffer: safe.)
#pragma unroll
    for (int i = 0; i < 4; ++i) produce_tile(buf ^ 1, i);
    if (chunk < 62) loadQ(chunk + 2);   // after produce (produce consumed aqp)
    // --- consume half1 (va0, m0..31); interleave r-read issue per nt ---
    s16x8 rr[8];
#pragma unroll
    for (int nt = 0; nt < 8; ++nt) {
#pragma unroll
      for (int ci = 0; ci < 4; ++ci) acc[ci][nt] = MFMA16(va0[ci], pg[nt], acc[ci][nt]);
      rr[nt] = *(const s16x8*)(P + (nt * 16 + l15) * 128 + ((4 + quad) ^ swz) * 16);
    }
    // --- va0 dead: prefetch next chunk's va0 (L2 latency hides under half2) ---
    if (chunk < 63) loadV0(chunk + 1);
    // --- consume half2 (va1, m32..63) ---
#pragma unroll
    for (int nt = 0; nt < 8; ++nt)
#pragma unroll
      for (int ci = 0; ci < 4; ++ci) acc[ci][nt] = MFMA16(va1[ci], rr[nt], acc[ci][nt]);
    // --- prefetch next chunk's va1 ---
    if (chunk < 63) loadV1(chunk + 1);
  }

  float* out_b = out + (size_t)b * 512 * 4096;
#pragma unroll
  for (int ci = 0; ci < 4; ++ci)
#pragma unroll
    for (int nt = 0; nt < 8; ++nt) {
      const int n = nbase + nt * 16 + l15;
      const int c0 = cbase + ci * 16 + quad * 4;
#pragma unroll
      for (int r = 0; r < 4; ++r) out_b[(size_t)(c0 + r) * 4096 + n] = acc[ci][nt][r];
    }
}

// ---------------- launch ----------------
extern "C" void kernel_launch(void* const* d_in, const int* in_sizes, int n_in,
                              void* d_out, int out_size, void* d_ws, size_t ws_size,
                              hipStream_t stream) {
  const float* x  = (const float*)d_in[0];   // [8,512,64,64]
  const float* Wq = (const float*)d_in[1];   // [32,512]
  const float* Wk = (const float*)d_in[2];   // [32,512]
  const float* Wv = (const float*)d_in[3];   // [512,512]
  float* out = (float*)d_out;                // [8,512,64,64]

  char* ws = (char*)d_ws;
  ushort* vb  = (ushort*)(ws + 0);           // 33,554,432 B
  ushort* xT  = (ushort*)(ws + 33554432);    // 33,554,432 B
  ushort* qb  = (ushort*)(ws + 67108864);    //  2,097,152 B
  ushort* kb  = (ushort*)(ws + 69206016);    //  2,097,152 B
  ushort* Wvb = (ushort*)(ws + 71303168);    //    524,288 B
  ushort* Wqb = (ushort*)(ws + 71827456);    //     32,768 B
  ushort* Wkb = (ushort*)(ws + 71860224);    //     32,768 B
  float*  Lrs = (float*)(ws + 71892992);     //    131,072 B  (total 72,024,064)

  hipLaunchKernelGGL(k_cvt_w, dim3(1152), dim3(256), 0, stream, Wq, Wk, Wv, Wqb, Wkb, Wvb);
  hipLaunchKernelGGL(k_xpose, dim3(16, 8, 8), dim3(256), 0, stream, x, xT);
  hipLaunchKernelGGL(k_proj, dim3(64, 8), dim3(256), 0, stream, xT, Wqb, Wkb, Wvb, qb, kb, vb);
  hipLaunchKernelGGL(k_pass1, dim3(64, 8), dim3(256), 0, stream, qb, kb, Lrs);
  hipLaunchKernelGGL(k_pass2, dim3(256), dim3(512), 0, stream, qb, kb, vb, Lrs, out);
}

// Round 5
// 346.012 us; speedup vs baseline: 1.0602x; 1.0602x over previous
//
#include <hip/hip_runtime.h>
#include <hip/hip_bf16.h>

// SelfAttention non-local block: B=8, C=512, N=4096, CQK=32.  All-MFMA bf16 path.
// v8:
//  - k_pass2 raw barrier: __syncthreads() compiles to s_waitcnt vmcnt(0)
//    lgkmcnt(0) + s_barrier, which drained the end-of-chunk V/Q prefetches at
//    EVERY chunk-top barrier (64x exposed L2 latency; ~3500 cyc/chunk of stall
//    vs 2190 cyc MFMA). Replaced with s_waitcnt lgkmcnt(0) (publishes P
//    ds_writes) + raw s_barrier + sched_barrier(0): global register-loads stay
//    in flight across the barrier; the compiler's counted vmcnt covers them
//    half a chunk later. (T4/m218: never vmcnt(0) at a main-loop barrier.)
//  - k_proj reverted to v6 (v7's B-frag pipeline regressed aux ~9us).
// ws: vb 33.5MB | xT 33.5MB | qb 2MB | kb 2MB | Wvb 512KB | Wqb 32KB | Wkb 32KB | Lneg 128KB

typedef __attribute__((ext_vector_type(8))) short s16x8;
typedef __attribute__((ext_vector_type(4))) float f32x4;

#define MFMA16(a, b, c) __builtin_amdgcn_mfma_f32_16x16x32_bf16((a), (b), (c), 0, 0, 0)

__device__ __forceinline__ ushort f2bf(float f) {
  union { float f; unsigned u; } v; v.f = f;
  return (ushort)((v.u + 0x8000u) >> 16);
}
__device__ __forceinline__ unsigned pack_bf16(float lo, float hi) {  // (hi<<16)|lo
  union { float f; unsigned u; } a, b; a.f = lo; b.f = hi;
  return __builtin_amdgcn_perm(b.u + 0x8000u, a.u + 0x8000u, 0x07060302u);
}
__device__ __forceinline__ float fexp2(float x) { return __builtin_amdgcn_exp2f(x); }

// Raw chunk barrier: publish DS writes, sync, but leave global loads in flight.
__device__ __forceinline__ void chunk_barrier() {
  asm volatile("s_waitcnt lgkmcnt(0)" ::: "memory");
  __builtin_amdgcn_s_barrier();
  __builtin_amdgcn_sched_barrier(0);
}

// ---------------- kernel 1: weights -> bf16 (Wq pre-scaled by log2e) ----------------
__global__ void k_cvt_w(const float* __restrict__ Wq, const float* __restrict__ Wk,
                        const float* __restrict__ Wv, ushort* __restrict__ Wqb,
                        ushort* __restrict__ Wkb, ushort* __restrict__ Wvb) {
  int i = blockIdx.x * 256 + threadIdx.x;
  if (i < 262144) Wvb[i] = f2bf(Wv[i]);
  else if (i < 278528) Wqb[i - 262144] = f2bf(Wq[i - 262144] * 1.4426950408889634f);
  else if (i < 294912) Wkb[i - 278528] = f2bf(Wk[i - 278528]);
}

// ---------------- kernel 2: transpose x -> xT bf16 ----------------
// Tile 64c x 256n. Phase1: float4 row loads (1KB contiguous per row), pack n-pairs,
// SoA LDS U[2][64][65] (even/odd pair split => <=2-way banks). Phase2: 8-lane groups
// build 128B-contiguous xT rows via v_perm extraction.
__global__ __launch_bounds__(256) void k_xpose(const float* __restrict__ x,
                                               ushort* __restrict__ xT) {
  const int b = blockIdx.z, c0 = blockIdx.y * 64, n0 = blockIdx.x * 256;
  __shared__ uint U[2][64][65];
  const int t = threadIdx.x;
  const int wv = t >> 6, ln = t & 63;
  const float* xp = x + ((size_t)b * 512 + c0 + wv * 16) * 4096 + n0 + ln * 4;
#pragma unroll
  for (int i = 0; i < 16; ++i) {
    float4 f = *(const float4*)(xp + (size_t)i * 4096);
    U[0][wv * 16 + i][ln] = pack_bf16(f.x, f.y);   // pairs (4ln,4ln+1)   -> pair idx 2ln
    U[1][wv * 16 + i][ln] = pack_bf16(f.z, f.w);   // pairs (4ln+2,4ln+3) -> pair idx 2ln+1
  }
  __syncthreads();
  const int c_seg = (t & 7) * 8;
#pragma unroll
  for (int pass = 0; pass < 8; ++pass) {
    const int nl = pass * 32 + (t >> 3);
    const int p = nl >> 1;              // pair index
    const int h = p & 1, idx = p >> 1;  // SoA half, slot
    const uint sel = (nl & 1) ? 0x07060302u : 0x05040100u;
    uint o[4];
#pragma unroll
    for (int j = 0; j < 4; ++j) {
      uint ua = U[h][c_seg + 2 * j][idx];
      uint ub = U[h][c_seg + 2 * j + 1][idx];
      o[j] = __builtin_amdgcn_perm(ub, ua, sel);   // (bf(c_odd)<<16)|bf(c_even)
    }
    *(uint4*)(xT + ((size_t)b * 4096 + n0 + nl) * 512 + c0 + c_seg) = *(uint4*)o;
  }
}

// ---------------- kernel 3: fused q/k/v projection from xT ----------------
__global__ __launch_bounds__(256, 2) void k_proj(const ushort* __restrict__ xT,
                                                 const ushort* __restrict__ Wqb,
                                                 const ushort* __restrict__ Wkb,
                                                 const ushort* __restrict__ Wvb,
                                                 ushort* __restrict__ qb,
                                                 ushort* __restrict__ kb,
                                                 ushort* __restrict__ vb) {
  const int b = blockIdx.y, n0 = blockIdx.x * 64;
  const int lane = threadIdx.x & 63, w = threadIdx.x >> 6;
  const int quad = lane >> 4, l15 = lane & 15;
  const ushort* xT_b = xT + (size_t)b * 4096 * 512;

  const ushort* Wqk = (w < 2) ? (Wqb + (size_t)(w * 16 + l15) * 512)
                              : (Wkb + (size_t)((w - 2) * 16 + l15) * 512);

  f32x4 accv[8][4], accqk[4];
#pragma unroll
  for (int i = 0; i < 8; ++i)
#pragma unroll
    for (int nt = 0; nt < 4; ++nt) accv[i][nt] = {0.f, 0.f, 0.f, 0.f};
#pragma unroll
  for (int nt = 0; nt < 4; ++nt) accqk[nt] = {0.f, 0.f, 0.f, 0.f};

  for (int k0 = 0; k0 < 512; k0 += 32) {
    s16x8 bx[4];
#pragma unroll
    for (int nt = 0; nt < 4; ++nt)
      bx[nt] = *(const s16x8*)(xT_b + (size_t)(n0 + nt * 16 + l15) * 512 + k0 + quad * 8);
#pragma unroll
    for (int i = 0; i < 8; ++i) {
      s16x8 av = *(const s16x8*)(Wvb + (size_t)((8 * w + i) * 16 + l15) * 512 + k0 + quad * 8);
#pragma unroll
      for (int nt = 0; nt < 4; ++nt) accv[i][nt] = MFMA16(av, bx[nt], accv[i][nt]);
    }
    s16x8 aqk = *(const s16x8*)(Wqk + k0 + quad * 8);
#pragma unroll
    for (int nt = 0; nt < 4; ++nt) accqk[nt] = MFMA16(aqk, bx[nt], accqk[nt]);
  }

  ushort* vb_b = vb + (size_t)b * 512 * 4096;
#pragma unroll
  for (int i = 0; i < 8; ++i)
#pragma unroll
    for (int nt = 0; nt < 4; ++nt)
#pragma unroll
      for (int r = 0; r < 4; ++r)
        vb_b[(size_t)((8 * w + i) * 16 + quad * 4 + r) * 4096 + n0 + nt * 16 + l15] =
            f2bf(accv[i][nt][r]);

  ushort* qk_out = (w < 2) ? (qb + (size_t)b * 4096 * 32) : (kb + (size_t)b * 4096 * 32);
#pragma unroll
  for (int nt = 0; nt < 4; ++nt) {
    ushort4 u;
    u.x = f2bf(accqk[nt][0]); u.y = f2bf(accqk[nt][1]);
    u.z = f2bf(accqk[nt][2]); u.w = f2bf(accqk[nt][3]);
    *(ushort4*)(qk_out + (size_t)(n0 + nt * 16 + l15) * 32 + (w & 1) * 16 + quad * 4) = u;
  }
}

// ---------------- kernel 4: pass1 — Lneg[b][m] = -log2(sum_n 2^(S'[m,n])) ----------------
__global__ __launch_bounds__(256) void k_pass1(const ushort* __restrict__ qb,
                                               const ushort* __restrict__ kb,
                                               float* __restrict__ Lneg) {
  const int b = blockIdx.y, mt = blockIdx.x;
  const int lane = threadIdx.x & 63, w = threadIdx.x >> 6;
  const int quad = lane >> 4, l15 = lane & 15;
  const int m = mt * 64 + w * 16;
  const ushort* qb_b = qb + (size_t)b * 4096 * 32;
  const ushort* kb_b = kb + (size_t)b * 4096 * 32;
  const s16x8 aqf = *(const s16x8*)(qb_b + (size_t)(m + l15) * 32 + quad * 8);
  float ps[4] = {0.f, 0.f, 0.f, 0.f};
  const f32x4 zf = {0.f, 0.f, 0.f, 0.f};
  for (int n0 = 0; n0 < 4096; n0 += 64) {
#pragma unroll
    for (int nt = 0; nt < 4; ++nt) {
      s16x8 bk = *(const s16x8*)(kb_b + (size_t)(n0 + nt * 16 + l15) * 32 + quad * 8);
      f32x4 s = MFMA16(aqf, bk, zf);
#pragma unroll
      for (int r = 0; r < 4; ++r) ps[r] += fexp2(s[r]);
    }
  }
  for (int off = 1; off < 16; off <<= 1)
#pragma unroll
    for (int r = 0; r < 4; ++r) ps[r] += __shfl_xor(ps[r], off, 64);
  if (l15 == 0)
#pragma unroll
    for (int r = 0; r < 4; ++r)
      Lneg[(size_t)b * 4096 + m + quad * 4 + r] = -log2f(ps[r]);
}

// ---------------- kernel 5: pass2 — out = V @ 2^(S' + Lneg) ----------------
// Grid 256 = 8 b (XCD-aligned: blk&7) x 32 ntb. Block 8 waves (512 thr): tile
// 512c x 128n, chunk 64 m. Per chunk: raw barrier (lgkm only) -> issue 8 P-reads
// (m0..31) -> produce x4 (register-only inputs; hides the LDS burst) -> loadQ ->
// consume half1 (va0, r-reads interleaved per-nt) -> loadV0 -> consume half2
// (va1) -> loadV1.  Global prefetches stay in flight across the barrier.
__global__ __launch_bounds__(512, 2) void k_pass2(const ushort* __restrict__ qb,
                                                  const ushort* __restrict__ kb,
                                                  const ushort* __restrict__ vb,
                                                  const float* __restrict__ Lneg,
                                                  float* __restrict__ out) {
  const int blk = blockIdx.x;
  const int b = blk & 7, ntb = blk >> 3;
  const int nbase = ntb * 128;
  const int lane = threadIdx.x & 63, w = threadIdx.x >> 6;   // 8 waves
  const int quad = lane >> 4, l15 = lane & 15;
  const int cbase = w * 64;
  const int swz = l15 & 7;
  const int Mw = w >> 1;               // produce m-tile (0..3)
  const int Tb = (w & 1) * 4;          // produce n-tile base (0 or 4)

  __shared__ __align__(16) ushort PT[2][128 * 64];  // 32 KB; 16B-granule XOR swizzle

  const ushort* qb_b = qb + (size_t)b * 4096 * 32;
  const ushort* kb_b = kb + (size_t)b * 4096 * 32;
  const ushort* vb_b = vb + (size_t)b * 512 * 4096;
  const float* L_b = Lneg + (size_t)b * 4096;

  s16x8 kf[4];  // K rows for this wave's 4 produce n-tiles
#pragma unroll
  for (int i = 0; i < 4; ++i)
    kf[i] = *(const s16x8*)(kb_b + (size_t)(nbase + (Tb + i) * 16 + l15) * 32 + quad * 8);

  f32x4 acc[4][8];
#pragma unroll
  for (int ci = 0; ci < 4; ++ci)
#pragma unroll
    for (int nt = 0; nt < 8; ++nt) acc[ci][nt] = {0.f, 0.f, 0.f, 0.f};

  s16x8 aqp;        // prefetched q A-frag for next produce (single m-tile)
  float4 l4p;       // prefetched Lneg
  s16x8 va0[4], va1[4];  // v A-frags: m0..31 / m32..63 of current chunk

  auto loadQ = [&](int chunk) {
    const int m0 = chunk * 64;
    aqp = *(const s16x8*)(qb_b + (size_t)(m0 + Mw * 16 + l15) * 32 + quad * 8);
    l4p = *(const float4*)(L_b + m0 + Mw * 16 + quad * 4);
  };
  auto loadV0 = [&](int chunk) {
    const int m0 = chunk * 64;
#pragma unroll
    for (int ci = 0; ci < 4; ++ci)
      va0[ci] = *(const s16x8*)(vb_b + (size_t)(cbase + ci * 16 + l15) * 4096 + m0 + quad * 8);
  };
  auto loadV1 = [&](int chunk) {
    const int m0 = chunk * 64;
#pragma unroll
    for (int ci = 0; ci < 4; ++ci)
      va1[ci] = *(const s16x8*)(vb_b + (size_t)(cbase + ci * 16 + l15) * 4096 + m0 + 32 + quad * 8);
  };
  // one produce tile: QK MFMA (Lneg as C-in) -> exp2 -> pack -> ds_write.
  auto produce_tile = [&](int buf, int i) {
    char* Pw = (char*)&PT[buf][0];
    const int T = Tb + i;
    f32x4 cin; cin.x = l4p.x; cin.y = l4p.y; cin.z = l4p.z; cin.w = l4p.w;
    f32x4 s = MFMA16(aqp, kf[i], cin);               // S' + Lneg  (<= ~0)
    uint2 u;
    u.x = pack_bf16(fexp2(s.x), fexp2(s.y));
    u.y = pack_bf16(fexp2(s.z), fexp2(s.w));
    const int row = T * 16 + l15;
    const int gran = (2 * Mw + (quad >> 1)) ^ swz;
    *(uint2*)(Pw + row * 128 + gran * 16 + (quad & 1) * 8) = u;
  };

  loadQ(0);
#pragma unroll
  for (int i = 0; i < 4; ++i) produce_tile(0, i);    // prologue: produce chunk 0
  loadQ(1);
  loadV0(0);
  loadV1(0);

  for (int chunk = 0; chunk < 64; ++chunk) {
    const int buf = chunk & 1;
    chunk_barrier();   // lgkm drain + s_barrier; global prefetches stay in flight
    const char* P = (const char*)&PT[buf][0];
    // --- issue all half1 P reads (m0..31, nt 0..7) ---
    s16x8 pg[8];
#pragma unroll
    for (int nt = 0; nt < 8; ++nt)
      pg[nt] = *(const s16x8*)(P + (nt * 16 + l15) * 128 + (quad ^ swz) * 16);
    // --- produce chunk+1 into buf^1: register-only inputs, no dep on pg ---
    // (chunk 63's produce reuses aqp(63) and writes a never-read buffer: safe.)
#pragma unroll
    for (int i = 0; i < 4; ++i) produce_tile(buf ^ 1, i);
    if (chunk < 62) loadQ(chunk + 2);   // after produce (produce consumed aqp)
    // --- consume half1 (va0, m0..31); interleave r-read issue per nt ---
    s16x8 rr[8];
#pragma unroll
    for (int nt = 0; nt < 8; ++nt) {
#pragma unroll
      for (int ci = 0; ci < 4; ++ci) acc[ci][nt] = MFMA16(va0[ci], pg[nt], acc[ci][nt]);
      rr[nt] = *(const s16x8*)(P + (nt * 16 + l15) * 128 + ((4 + quad) ^ swz) * 16);
    }
    // --- va0 dead: prefetch next chunk's va0 (L2 latency hides under half2) ---
    if (chunk < 63) loadV0(chunk + 1);
    // --- consume half2 (va1, m32..63) ---
#pragma unroll
    for (int nt = 0; nt < 8; ++nt)
#pragma unroll
      for (int ci = 0; ci < 4; ++ci) acc[ci][nt] = MFMA16(va1[ci], rr[nt], acc[ci][nt]);
    // --- prefetch next chunk's va1 ---
    if (chunk < 63) loadV1(chunk + 1);
  }

  float* out_b = out + (size_t)b * 512 * 4096;
#pragma unroll
  for (int ci = 0; ci < 4; ++ci)
#pragma unroll
    for (int nt = 0; nt < 8; ++nt) {
      const int n = nbase + nt * 16 + l15;
      const int c0 = cbase + ci * 16 + quad * 4;
#pragma unroll
      for (int r = 0; r < 4; ++r) out_b[(size_t)(c0 + r) * 4096 + n] = acc[ci][nt][r];
    }
}

// ---------------- launch ----------------
extern "C" void kernel_launch(void* const* d_in, const int* in_sizes, int n_in,
                              void* d_out, int out_size, void* d_ws, size_t ws_size,
                              hipStream_t stream) {
  const float* x  = (const float*)d_in[0];   // [8,512,64,64]
  const float* Wq = (const float*)d_in[1];   // [32,512]
  const float* Wk = (const float*)d_in[2];   // [32,512]
  const float* Wv = (const float*)d_in[3];   // [512,512]
  float* out = (float*)d_out;                // [8,512,64,64]

  char* ws = (char*)d_ws;
  ushort* vb  = (ushort*)(ws + 0);           // 33,554,432 B
  ushort* xT  = (ushort*)(ws + 33554432);    // 33,554,432 B
  ushort* qb  = (ushort*)(ws + 67108864);    //  2,097,152 B
  ushort* kb  = (ushort*)(ws + 69206016);    //  2,097,152 B
  ushort* Wvb = (ushort*)(ws + 71303168);    //    524,288 B
  ushort* Wqb = (ushort*)(ws + 71827456);    //     32,768 B
  ushort* Wkb = (ushort*)(ws + 71860224);    //     32,768 B
  float*  Lrs = (float*)(ws + 71892992);     //    131,072 B  (total 72,024,064)

  hipLaunchKernelGGL(k_cvt_w, dim3(1152), dim3(256), 0, stream, Wq, Wk, Wv, Wqb, Wkb, Wvb);
  hipLaunchKernelGGL(k_xpose, dim3(16, 8, 8), dim3(256), 0, stream, x, xT);
  hipLaunchKernelGGL(k_proj, dim3(64, 8), dim3(256), 0, stream, xT, Wqb, Wkb, Wvb, qb, kb, vb);
  hipLaunchKernelGGL(k_pass1, dim3(64, 8), dim3(256), 0, stream, qb, kb, Lrs);
  hipLaunchKernelGGL(k_pass2, dim3(256), dim3(512), 0, stream, qb, kb, vb, Lrs, out);
}